// Round 10
// baseline (136.395 us; speedup 1.0000x reference)
//
#include <hip/hip_runtime.h>
#include <hip/hip_bf16.h>
#include <stdint.h>

// KAN layer, MI355X (gfx950) — V10: TWO-KERNEL SPLIT (spline | GEMM).
// out[M=65536, N=256] (fp32) = A[M, K=256] @ W^T,
//   A[m,k] = c0[k]*B0(tanh(x[m,k])) + c1[k]*B1(tanh(x[m,k])) -> bf16
//
// Why split (ladder evidence): fused best = 43.3us (V8) with ALL pipes <=35%.
//   V8 halved LDS+MFMA vs V3: ~0 gain. V9 gave the spline 8-wide stage ILP:
//   ~0 gain (VALUBusy even dropped). No spills (FETCH clean). => The wall is
//   latency-limbo at 2 waves/SIMD, forced by 131KB LDS + the occupancy quantum
//   (acc=128 AGPR + ~124 arch = 252 regs -> 8 waves/CU). Fusion caps occupancy;
//   splitting lets the spline run at FULL occupancy and leaves a lean GEMM.
//
// A-buffer trick: A (33.5MB bf16) lives inside d_out itself. k1 writes A for
//   rows [b*256+w*32, +32) into the FIRST 16KB of out's 32KB region for those
//   same rows (byte off: b*262144 + w*32768 + (m&31)*512 + k*2). k2's wave w of
//   block b reads ONLY that slice during its K-loop and overwrites it with fp32
//   output ONLY in its epilogue -> read-before-write is wave-private, no race.
//   k1 -> k2 ordering is stream order. No workspace-size assumptions.

typedef __attribute__((ext_vector_type(8))) short short8;    // 8 bf16 (MFMA A/B frag)
typedef __attribute__((ext_vector_type(16))) float f32x16;   // 32x32 MFMA C/D frag

__device__ __forceinline__ uint16_t f2bf(float f) {
    union { float f; uint32_t u; } v; v.f = f;
    uint32_t r = v.u + 0x7FFFu + ((v.u >> 16) & 1u);  // RNE
    return (uint16_t)(r >> 16);
}

__device__ __forceinline__ uint32_t pack_bf2(float lo, float hi) {
    __hip_bfloat162 h = __float22bfloat162_rn(make_float2(lo, hi));
    union { __hip_bfloat162 h; uint32_t u; } v; v.h = h;
    return v.u;
}

__device__ __forceinline__ float cube_relu(float v) {
    float m = fmaxf(v, 0.0f);
    return m * m * m;
}

__device__ __forceinline__ float inner_eval(float xx, float c0, float c1) {
    // tanh via exp: tanh(x) = 1 - 2/(e^{2x}+1); saturates correctly at +/-inf
    float e  = __expf(2.0f * xx);
    float t  = 1.0f - 2.0f * __builtin_amdgcn_rcpf(e + 1.0f);
    float u  = (t + 1.0f) * 3.5f;          // in [0,7]
    float w0 = cube_relu(u);
    float w1 = cube_relu(u - 1.0f);
    float w2 = cube_relu(u - 2.0f);
    float w3 = cube_relu(u - 3.0f);
    float w4 = cube_relu(u - 4.0f);
    float w5 = cube_relu(u - 5.0f);
    float B0 = w0 - 4.0f*w1 + 6.0f*w2 - 4.0f*w3 + w4;
    float B1 = w1 - 4.0f*w2 + 6.0f*w3 - 4.0f*w4 + w5;
    return (c0 * B0 + c1 * B1) * (1.0f / 6.0f);
}

__device__ __forceinline__ void load_lds16(const void* g, void* l) {
    __builtin_amdgcn_global_load_lds(
        (const __attribute__((address_space(1))) uint32_t*)g,
        (__attribute__((address_space(3))) uint32_t*)l, 16, 0, 0);
}

// W fp32 -> bf16 into the XOR-SWIZZLED layout kan_gemm's ds_reads expect:
//   value W[row][col] lands at byte  row*512 + ((col*2) ^ ((row&7)<<4)).
// Also packs the (c0,c1) coeff table at offset 131072 (2 KB) for spline_a.
__global__ void conv_w(const float* __restrict__ ic, const float4* __restrict__ wf,
                       char* __restrict__ o) {
    const int i = blockIdx.x * blockDim.x + threadIdx.x;  // 0..16383
    const float4 v = wf[i];
    uint2 r;
    r.x = (uint32_t)f2bf(v.x) | ((uint32_t)f2bf(v.y) << 16);
    r.y = (uint32_t)f2bf(v.z) | ((uint32_t)f2bf(v.w) << 16);
    const int row = i >> 6;           // 64 threads per 256-float row
    const int cb  = (i & 63) << 3;    // byte col within row, 8-aligned
    *(uint2*)(o + row * 512 + (cb ^ ((row & 7) << 4))) = r;
    if (i < 256)
        *(float2*)(o + 131072 + i * 8) = make_float2(ic[i * 5 + 0], ic[i * 5 + 1]);
}

// K1: spline. 8192 blocks x 256 thr, 8 elems/thread. No LDS, ~50 VGPR ->
// full occupancy; memory-bound streaming (read x 67MB, write A 33.5MB).
__global__ void __launch_bounds__(256) spline_a(const float* __restrict__ x,
                                                const char* __restrict__ wb,
                                                char* __restrict__ ab) {
    const int g  = blockIdx.x * 256 + threadIdx.x;   // 8-elem group id
    const int m  = g >> 5;            // row 0..65535
    const int kb = (g & 31) << 3;     // k base 0..248
    const float4 xa = *(const float4*)(x + (size_t)m * 256 + kb);
    const float4 xb = *(const float4*)(x + (size_t)m * 256 + kb + 4);
    const float4* c2g = (const float4*)(wb + 131072);  // packed (c0,c1) pairs
    const float4 cA = c2g[(kb >> 1) + 0];
    const float4 cB = c2g[(kb >> 1) + 1];
    const float4 cC = c2g[(kb >> 1) + 2];
    const float4 cD = c2g[(kb >> 1) + 3];
    float v0 = inner_eval(xa.x, cA.x, cA.y);
    float v1 = inner_eval(xa.y, cA.z, cA.w);
    float v2 = inner_eval(xa.z, cB.x, cB.y);
    float v3 = inner_eval(xa.w, cB.z, cB.w);
    float v4 = inner_eval(xb.x, cC.x, cC.y);
    float v5 = inner_eval(xb.y, cC.z, cC.w);
    float v6 = inner_eval(xb.z, cD.x, cD.y);
    float v7 = inner_eval(xb.w, cD.z, cD.w);
    uint4 r;
    r.x = pack_bf2(v0, v1);
    r.y = pack_bf2(v2, v3);
    r.z = pack_bf2(v4, v5);
    r.w = pack_bf2(v6, v7);
    // A slice layout: block b = m>>8, wave w = (m>>5)&7, row-in-wave = m&31
    char* A = ab + ((size_t)(m >> 8) << 18) + (((m >> 5) & 7) << 15)
                 + ((m & 31) << 9) + (kb << 1);
    *(uint4*)A = r;
}

// K2: GEMM. 256 blocks x 512 thr (8 waves, 1 block/CU). Wave w: rows
// [b*256+w*32, +32) x all 256 cols (8 n-tiles of 32x32x16). W whole in LDS
// (swizzled, V8-proven). A read per-lane 16B from the wave's own out-slice
// (L3-hot, just written by k1); out stored over it in the epilogue.
// Mappings (HW-verified V8): A: m=lane&31, k=(lane>>5)*8+e; B: n=lane&31;
//   C/D: col=lane&31, row=(r&3)+8*(r>>2)+4*(lane>>5).
__global__ void __launch_bounds__(512, 2) kan_gemm(const char* __restrict__ wb,
                                                   float* __restrict__ out) {
    __shared__ __align__(16) char Wlds[131072];

    const int t    = threadIdx.x;
    const int lane = t & 63;
    const int w    = t >> 6;
    const int col  = lane & 31;
    const int half = lane >> 5;
    const int swz  = (col & 7) << 4;

    // Stage all 128 KB of (pre-swizzled) W linearly: 16 rounds x 8 waves x 1 KB.
    #pragma unroll
    for (int it = 0; it < 16; ++it) {
        const int base = ((it * 8 + w) << 10) + lane * 16;
        load_lds16(wb + base, Wlds + base);
    }

    // This lane's A base: block region + wave slice + its row + its k-half.
    const char* Ar = (const char*)out + ((size_t)blockIdx.x << 18)
                   + (w << 15) + (col << 9) + (half << 4);

    __syncthreads();   // W staged

    f32x16 acc[8];
    #pragma unroll
    for (int j = 0; j < 8; ++j)
        #pragma unroll
        for (int r = 0; r < 16; ++r)
            acc[j][r] = 0.0f;

    // Full unroll: per-iter state is tiny (1 A-frag + 8 B-frags); compiler
    // pipelines loads across iters as registers permit (elective, no forced
    // cross-phase liveness -> no spill, unlike V5-V7).
    #pragma unroll
    for (int kk = 0; kk < 16; ++kk) {
        const short8 av = *(const short8*)(Ar + kk * 32);
        const int cw = (kk * 32 + half * 16) ^ swz;
        short8 b[8];
        #pragma unroll
        for (int j = 0; j < 8; ++j)
            b[j] = *(const short8*)(Wlds + ((j * 32 + col) << 9) + cw);
        #pragma unroll
        for (int j = 0; j < 8; ++j)
            acc[j] = __builtin_amdgcn_mfma_f32_32x32x16_bf16(av, b[j], acc[j], 0, 0, 0);
    }

    // Epilogue: overwrite this wave's region (incl. its A slice — all A-reads
    // were consumed by MFMAs above, so their waitcnts precede these stores).
    const int mb = blockIdx.x * 256 + w * 32;
    float* op = out + (size_t)(mb + 4 * half) * 256 + col;
    #pragma unroll
    for (int j = 0; j < 8; ++j) {
        #pragma unroll
        for (int r = 0; r < 16; ++r)
            op[(size_t)((r & 3) + 8 * (r >> 2)) * 256 + j * 32] = acc[j][r];
    }
}

extern "C" void kernel_launch(void* const* d_in, const int* in_sizes, int n_in,
                              void* d_out, int out_size, void* d_ws, size_t ws_size,
                              hipStream_t stream) {
    const float* x  = (const float*)d_in[0];   // [16,4096,256] fp32
    const float* ic = (const float*)d_in[1];   // [256,5] fp32
    const float* oc = (const float*)d_in[2];   // [256,256] fp32
    char* wb = (char*)d_ws;                    // 128 KB swizzled W + 2 KB coeffs

    conv_w<<<64, 256, 0, stream>>>(ic, (const float4*)oc, wb);
    spline_a<<<8192, 256, 0, stream>>>(x, wb, (char*)d_out);
    kan_gemm<<<256, 512, 0, stream>>>(wb, (float*)d_out);
}